// Round 4
// baseline (44.813 us; speedup 1.0000x reference)
//
#include <hip/hip_runtime.h>
#include <math.h>

#define NBLK 2048      // one block per (b,f) row of N=1024 points
#define NTHR 256
#define NIT  4         // 4 tiles x 256 points = 1024 points per block
#define B_ 4
#define F_ 512
#define N_ 1024
#define V_ 4

// LDS staging layout (byte offsets), all 1 KB-chunk aligned
#define L_PRED 0        // 3072 B  (256 pts * 12 B)
#define L_GT   3072     // 3072 B
#define L_NB1  6144     // 3072 B
#define L_NB2  9216     // 3072 B
#define L_VIS  12288    // 1024 B  (256 * int)
#define L_TRK  13312    // 4 views * 2048 B
#define L_TOT  21504

struct Partial {          // 64 B, all f32
  float sum_diff2;
  float sum_dist;
  float sum_acc2;
  float cnt;
  float gmin[3], gmax[3], pmin[3], pmax[3];
};

__device__ __forceinline__ void gl_lds16(const void* g, void* l) {
  __builtin_amdgcn_global_load_lds(
      (const __attribute__((address_space(1))) void*)g,
      (__attribute__((address_space(3))) void*)l, 16, 0, 0);
}

__global__ __launch_bounds__(NTHR) void loss_main(
    const float* __restrict__ pred, const float* __restrict__ gt,
    const int* __restrict__ vis, const float* __restrict__ P,
    const float* __restrict__ tracks, Partial* __restrict__ partials)
{
  __shared__ __align__(16) char sbuf[L_TOT];
  __shared__ float sP[V_ * 12];          // this block's 4 projection mats
  __shared__ Partial sw[NTHR / 64];

  const int r = blockIdx.x;              // row id = b*F + f
  const int b = r >> 9;
  const int f = r & (F_ - 1);
  const bool has_acc = (f < F_ - 2);
  const size_t nb1Off = has_acc ? (size_t)(N_ * 12) : 0;      // bytes
  const size_t nb2Off = has_acc ? (size_t)(2 * N_ * 12) : 0;
  const size_t rowPt = (size_t)r << 10;  // first point of row

  const int t = threadIdx.x;
  const int wave = t >> 6, lane = t & 63;

  if (t < V_ * 12) {                     // 48 floats: P[(v*B+b)][...]
    const int v = t / 12, j = t - v * 12;
    sP[t] = P[((v * B_ + b) * 12) + j];
  }

  float sum_diff2 = 0.0f, sum_dist = 0.0f, sum_acc2 = 0.0f, cntf = 0.0f;
  float gmin[3] = { INFINITY,  INFINITY,  INFINITY};
  float gmax[3] = {-INFINITY, -INFINITY, -INFINITY};
  float pmin[3] = { INFINITY,  INFINITY,  INFINITY};
  float pmax[3] = {-INFINITY, -INFINITY, -INFINITY};

  const float* sF   = (const float*)sbuf;
  const int*   sVis = (const int*)(sbuf + L_VIS);

  for (int it = 0; it < NIT; ++it) {
    const size_t e0 = rowPt + (size_t)(it << 8);   // tile first point
    const char* pred_b = (const char*)pred + e0 * 12;
    const char* gt_b   = (const char*)gt   + e0 * 12;
    const char* vis_b  = (const char*)vis  + e0 * 4;
    const size_t ew2 = (e0 & ((size_t)F_ * N_ - 1)) << 1;  // float idx in view-batch

    // ---- stage 21 x 1KB chunks, fire-and-forget (wave-uniform c)
    for (int c = wave; c < 21; c += 4) {
      const char* src;
      int lo;
      if (c < 12) {
        const int arr = c / 3, k = c - arr * 3;
        const char* base = (arr == 1) ? gt_b : pred_b;
        const size_t extra = (arr == 2) ? nb1Off : (arr == 3) ? nb2Off : 0;
        src = base + extra + (size_t)(k << 10);
        lo = arr * 3072 + (k << 10);
      } else if (c == 12) {
        src = vis_b;
        lo = L_VIS;
      } else {
        const int u = c - 13, v = u >> 1, k = u & 1;
        const size_t fb = ((size_t)(v * B_ + b) << 20) + ew2;  // float index
        src = (const char*)(tracks + fb) + (size_t)(k << 10);
        lo = L_TRK + v * 2048 + (k << 10);
      }
      gl_lds16(src + lane * 16, sbuf + lo);
    }
    __syncthreads();   // drains vmcnt -> all 21 KB present; also sP visible

    // ---- compute: thread t owns point e0 + t
    const float px = sF[3 * t],        py = sF[3 * t + 1],        pz = sF[3 * t + 2];
    const float gx = sF[768 + 3 * t],  gy = sF[768 + 3 * t + 1],  gz = sF[768 + 3 * t + 2];
    const int   vm = sVis[t];

    pmin[0] = fminf(pmin[0], px); pmax[0] = fmaxf(pmax[0], px);
    pmin[1] = fminf(pmin[1], py); pmax[1] = fmaxf(pmax[1], py);
    pmin[2] = fminf(pmin[2], pz); pmax[2] = fmaxf(pmax[2], pz);

    if (vm) {
      const float d0 = px - gx, d1 = py - gy, d2 = pz - gz;
      sum_diff2 += d0 * d0 + d1 * d1 + d2 * d2;
      cntf += 1.0f;
      gmin[0] = fminf(gmin[0], gx); gmax[0] = fmaxf(gmax[0], gx);
      gmin[1] = fminf(gmin[1], gy); gmax[1] = fmaxf(gmax[1], gy);
      gmin[2] = fminf(gmin[2], gz); gmax[2] = fmaxf(gmax[2], gz);
    }

    if (has_acc) {
      const float ax = sF[1536 + 3 * t], ay = sF[1536 + 3 * t + 1], az = sF[1536 + 3 * t + 2];
      const float cx = sF[2304 + 3 * t], cy = sF[2304 + 3 * t + 1], cz = sF[2304 + 3 * t + 2];
      const float a0 = cx - 2.0f * ax + px;
      const float a1 = cy - 2.0f * ay + py;
      const float a2 = cz - 2.0f * az + pz;
      sum_acc2 += a0 * a0 + a1 * a1 + a2 * a2;
    }

#pragma unroll
    for (int v = 0; v < V_; ++v) {
      const float* Pm = sP + v * 12;
      const float a0 = Pm[0] * px + Pm[1] * py + Pm[2]  * pz + Pm[3];
      const float a1 = Pm[4] * px + Pm[5] * py + Pm[6]  * pz + Pm[7];
      const float a2 = Pm[8] * px + Pm[9] * py + Pm[10] * pz + Pm[11];
      const float inv = 1.0f / (a2 + 1e-10f);
      const float dx = a0 * inv - sF[3328 + v * 512 + 2 * t];
      const float dy = a1 * inv - sF[3328 + v * 512 + 2 * t + 1];
      sum_dist += dx * dx + dy * dy;
    }

    __syncthreads();   // compute done before next stage overwrites LDS
  }

  // ---- wave shuffle reduction (f32, deterministic tree)
#pragma unroll
  for (int o = 32; o > 0; o >>= 1) {
    sum_diff2 += __shfl_down(sum_diff2, o);
    sum_dist  += __shfl_down(sum_dist,  o);
    sum_acc2  += __shfl_down(sum_acc2,  o);
    cntf      += __shfl_down(cntf,      o);
#pragma unroll
    for (int k = 0; k < 3; ++k) {
      gmin[k] = fminf(gmin[k], __shfl_down(gmin[k], o));
      gmax[k] = fmaxf(gmax[k], __shfl_down(gmax[k], o));
      pmin[k] = fminf(pmin[k], __shfl_down(pmin[k], o));
      pmax[k] = fmaxf(pmax[k], __shfl_down(pmax[k], o));
    }
  }

  if (lane == 0) {
    Partial p;
    p.sum_diff2 = sum_diff2; p.sum_dist = sum_dist;
    p.sum_acc2  = sum_acc2;  p.cnt      = cntf;
#pragma unroll
    for (int k = 0; k < 3; ++k) {
      p.gmin[k] = gmin[k]; p.gmax[k] = gmax[k];
      p.pmin[k] = pmin[k]; p.pmax[k] = pmax[k];
    }
    sw[wave] = p;
  }
  __syncthreads();
  if (t == 0) {
    Partial p = sw[0];
#pragma unroll
    for (int w = 1; w < NTHR / 64; ++w) {
      p.sum_diff2 += sw[w].sum_diff2; p.sum_dist += sw[w].sum_dist;
      p.sum_acc2  += sw[w].sum_acc2;  p.cnt      += sw[w].cnt;
#pragma unroll
      for (int k = 0; k < 3; ++k) {
        p.gmin[k] = fminf(p.gmin[k], sw[w].gmin[k]);
        p.gmax[k] = fmaxf(p.gmax[k], sw[w].gmax[k]);
        p.pmin[k] = fminf(p.pmin[k], sw[w].pmin[k]);
        p.pmax[k] = fmaxf(p.pmax[k], sw[w].pmax[k]);
      }
    }
    partials[blockIdx.x] = p;
  }
}

__global__ __launch_bounds__(NTHR) void loss_final(
    const Partial* __restrict__ partials, float* __restrict__ out)
{
  float sum_diff2 = 0.0f, sum_dist = 0.0f, sum_acc2 = 0.0f, cnt = 0.0f;
  float gmin[3] = { INFINITY,  INFINITY,  INFINITY};
  float gmax[3] = {-INFINITY, -INFINITY, -INFINITY};
  float pmin[3] = { INFINITY,  INFINITY,  INFINITY};
  float pmax[3] = {-INFINITY, -INFINITY, -INFINITY};

  const int tid = threadIdx.x;
  for (int i = tid; i < NBLK; i += NTHR) {   // fixed order -> deterministic
    const Partial p = partials[i];
    sum_diff2 += p.sum_diff2; sum_dist += p.sum_dist;
    sum_acc2  += p.sum_acc2;  cnt      += p.cnt;
#pragma unroll
    for (int k = 0; k < 3; ++k) {
      gmin[k] = fminf(gmin[k], p.gmin[k]); gmax[k] = fmaxf(gmax[k], p.gmax[k]);
      pmin[k] = fminf(pmin[k], p.pmin[k]); pmax[k] = fmaxf(pmax[k], p.pmax[k]);
    }
  }

#pragma unroll
  for (int o = 32; o > 0; o >>= 1) {
    sum_diff2 += __shfl_down(sum_diff2, o);
    sum_dist  += __shfl_down(sum_dist,  o);
    sum_acc2  += __shfl_down(sum_acc2,  o);
    cnt       += __shfl_down(cnt,       o);
#pragma unroll
    for (int k = 0; k < 3; ++k) {
      gmin[k] = fminf(gmin[k], __shfl_down(gmin[k], o));
      gmax[k] = fmaxf(gmax[k], __shfl_down(gmax[k], o));
      pmin[k] = fminf(pmin[k], __shfl_down(pmin[k], o));
      pmax[k] = fmaxf(pmax[k], __shfl_down(pmax[k], o));
    }
  }

  __shared__ Partial sw[NTHR / 64];
  const int lane = tid & 63;
  const int wave = tid >> 6;
  if (lane == 0) {
    Partial p;
    p.sum_diff2 = sum_diff2; p.sum_dist = sum_dist;
    p.sum_acc2  = sum_acc2;  p.cnt      = cnt;
#pragma unroll
    for (int k = 0; k < 3; ++k) {
      p.gmin[k] = gmin[k]; p.gmax[k] = gmax[k];
      p.pmin[k] = pmin[k]; p.pmax[k] = pmax[k];
    }
    sw[wave] = p;
  }
  __syncthreads();

  if (tid == 0) {
    Partial p = sw[0];
#pragma unroll
    for (int w = 1; w < NTHR / 64; ++w) {
      p.sum_diff2 += sw[w].sum_diff2; p.sum_dist += sw[w].sum_dist;
      p.sum_acc2  += sw[w].sum_acc2;  p.cnt      += sw[w].cnt;
#pragma unroll
      for (int k = 0; k < 3; ++k) {
        p.gmin[k] = fminf(p.gmin[k], sw[w].gmin[k]);
        p.gmax[k] = fmaxf(p.gmax[k], sw[w].gmax[k]);
        p.pmin[k] = fminf(p.pmin[k], sw[w].pmin[k]);
        p.pmax[k] = fmaxf(p.pmax[k], sw[w].pmax[k]);
      }
    }

    double sr = -INFINITY;
#pragma unroll
    for (int k = 0; k < 3; ++k) sr = fmax(sr, (double)p.gmax[k] - (double)p.gmin[k]);
    sr += 1e-6;
    const double recon = (double)p.sum_diff2 / fmax((double)p.cnt * 3.0, 1.0) / (sr * sr);

    const double ident = (double)p.sum_dist / 224.0 / ((double)V_ * B_ * F_ * N_ * 2.0);

    double st = -INFINITY;
#pragma unroll
    for (int k = 0; k < 3; ++k) st = fmax(st, (double)p.pmax[k] - (double)p.pmin[k]);
    st += 1e-6;
    const double tloss = (double)p.sum_acc2 / ((double)B_ * (F_ - 2) * N_);
    const double temp = tloss / (st * st);

    const double total = recon + ident + 0.5 * temp;
    out[0] = (float)total;
    out[1] = (float)recon;
    out[2] = (float)ident;
    out[3] = (float)temp;
  }
}

extern "C" void kernel_launch(void* const* d_in, const int* in_sizes, int n_in,
                              void* d_out, int out_size, void* d_ws, size_t ws_size,
                              hipStream_t stream) {
  const float* pred   = (const float*)d_in[0];
  const float* gt     = (const float*)d_in[1];
  const int*   vis    = (const int*)d_in[2];
  const float* P      = (const float*)d_in[3];
  const float* tracks = (const float*)d_in[4];
  float* out = (float*)d_out;
  Partial* partials = (Partial*)d_ws;

  loss_main<<<NBLK, NTHR, 0, stream>>>(pred, gt, vis, P, tracks, partials);
  loss_final<<<1, NTHR, 0, stream>>>(partials, out);
}

// Round 5
// 36.735 us; speedup vs baseline: 1.2199x; 1.2199x over previous
//
#include <hip/hip_runtime.h>
#include <math.h>

#define NTHR 256
#define CF   8                      // frames per block
#define NBLK (4 * 64 * 4)           // B * (F/CF) * quarters = 1024
#define B_ 4
#define F_ 512
#define N_ 1024
#define V_ 4
#define QN 256                      // points per phase (quarter row)

// LDS byte layout inside sbuf
#define L_PRED 0                    // 4 rotating slots x 3072 B
#define L_CONS (4 * 3072)           // 2 buffers x 12288 B (gt 3072 | vis 1024 | trk 8192)
#define L_SCR  (L_CONS + 2 * 12288) // 1024 B dummy sink
#define L_TOT  (L_SCR + 1024)      // 37888 B

struct Partial {                    // 64 B, all f32
  float sum_diff2, sum_dist, sum_acc2, cnt;
  float gmin[3], gmax[3], pmin[3], pmax[3];
};

__device__ __forceinline__ void gl_lds16(const void* g, void* l) {
  __builtin_amdgcn_global_load_lds(
      (const __attribute__((address_space(1))) void*)g,
      (__attribute__((address_space(3))) void*)l, 16, 0, 0);
}

__global__ __launch_bounds__(NTHR) void loss_main(
    const float* __restrict__ pred, const float* __restrict__ gt,
    const int* __restrict__ vis, const float* __restrict__ P,
    const float* __restrict__ tracks, Partial* __restrict__ partials)
{
  __shared__ __align__(16) char sbuf[L_TOT];
  __shared__ float sP[V_ * 12];
  __shared__ Partial sw[NTHR / 64];

  const int bid = blockIdx.x;
  const int b  = bid >> 8;                 // batch
  const int fc = (bid >> 2) & 63;          // frame chunk
  const int qr = bid & 3;                  // quarter of the N row
  const int f0 = fc << 3;
  const int n0 = qr << 8;

  const int t = threadIdx.x;
  const int wave = t >> 6, lane = t & 63;

  if (t < V_ * 12) {                       // projection mats for this b
    const int v = t / 12, j = t - v * 12;
    sP[t] = P[(v * B_ + b) * 12 + j];
  }

  // ---------------- prologue: pred rows f0..f0+2, cons frame f0 (24 chunks, 6/wave)
  {
    const size_t gtB0  = ((size_t)(b * F_ + f0) * N_ + n0) * 12;
    const size_t visB0 = ((size_t)(b * F_ + f0) * N_ + n0) * 4;
    char* cons0 = sbuf + L_CONS;
    for (int c = wave; c < 24; c += 4) {
      const char* src; char* dst;
      if (c < 9) {
        const int r = c / 3, k = c - r * 3;
        src = (const char*)pred + ((size_t)(b * F_ + f0 + r) * N_ + n0) * 12 + (k << 10);
        dst = sbuf + L_PRED + r * 3072 + (k << 10);
      } else if (c < 21) {
        const int u = c - 9;
        if (u < 3)      { src = (const char*)gt + gtB0 + (u << 10); dst = cons0 + (u << 10); }
        else if (u == 3){ src = (const char*)vis + visB0;           dst = cons0 + 3072; }
        else {
          const int w2 = u - 4, v = w2 >> 1, k = w2 & 1;
          src = (const char*)tracks + (((size_t)(v * B_ + b) * F_ + f0) * N_ + n0) * 8 + ((size_t)k << 10);
          dst = cons0 + 4096 + v * 2048 + (k << 10);
        }
      } else { src = (const char*)pred; dst = sbuf + L_SCR; }
      gl_lds16(src + lane * 16, dst);
    }
  }

  float sum_diff2 = 0.0f, sum_dist = 0.0f, sum_acc2 = 0.0f, cntf = 0.0f;
  float gmin[3] = { INFINITY,  INFINITY,  INFINITY};
  float gmax[3] = {-INFINITY, -INFINITY, -INFINITY};
  float pmin[3] = { INFINITY,  INFINITY,  INFINITY};
  float pmax[3] = {-INFINITY, -INFINITY, -INFINITY};

  for (int i = 0; i < CF; ++i) {
    const int fi = f0 + i;

    // ---- issue next-phase prefetch (16 chunks, exactly 4 per wave)
    {
      const int rowPre  = (fi + 3 < F_) ? fi + 3 : F_ - 1;
      const int rowCons = (fi + 1 < F_) ? fi + 1 : F_ - 1;
      const size_t preB = ((size_t)(b * F_ + rowPre)  * N_ + n0) * 12;
      const size_t gtB  = ((size_t)(b * F_ + rowCons) * N_ + n0) * 12;
      const size_t visB = ((size_t)(b * F_ + rowCons) * N_ + n0) * 4;
      char* consD = sbuf + L_CONS + ((i + 1) & 1) * 12288;
      char* predD = sbuf + L_PRED + ((i + 3) & 3) * 3072;
      for (int c = wave; c < 16; c += 4) {
        const char* src; char* dst;
        if (c < 3)        { src = (const char*)pred + preB + (c << 10); dst = predD + (c << 10); }
        else if (c < 6)   { const int k = c - 3;
                            src = (const char*)gt + gtB + (k << 10);    dst = consD + (k << 10); }
        else if (c == 6)  { src = (const char*)vis + visB;              dst = consD + 3072; }
        else if (c < 15)  { const int u = c - 7, v = u >> 1, k = u & 1;
                            src = (const char*)tracks + (((size_t)(v * B_ + b) * F_ + rowCons) * N_ + n0) * 8 + ((size_t)k << 10);
                            dst = consD + 4096 + v * 2048 + (k << 10); }
        else              { src = (const char*)pred;                    dst = sbuf + L_SCR; }
        gl_lds16(src + lane * 16, dst);
      }
    }

    // ---- wait current frame's data (4 newest loads stay in flight), sync
    asm volatile("s_waitcnt vmcnt(4) lgkmcnt(0)\n\ts_barrier" ::: "memory");

    // ---- compute frame fi
    {
      const float* sPd = (const float*)(sbuf + L_PRED + ((i    ) & 3) * 3072);
      const float* sN1 = (const float*)(sbuf + L_PRED + ((i + 1) & 3) * 3072);
      const float* sN2 = (const float*)(sbuf + L_PRED + ((i + 2) & 3) * 3072);
      const char*  cc  = sbuf + L_CONS + (i & 1) * 12288;
      const float* sG  = (const float*)cc;
      const int*   sV  = (const int*)(cc + 3072);
      const float* sT  = (const float*)(cc + 4096);

      const float px = sPd[3 * t], py = sPd[3 * t + 1], pz = sPd[3 * t + 2];
      const float gx = sG[3 * t],  gy = sG[3 * t + 1],  gz = sG[3 * t + 2];
      const int   vm = sV[t];

      pmin[0] = fminf(pmin[0], px); pmax[0] = fmaxf(pmax[0], px);
      pmin[1] = fminf(pmin[1], py); pmax[1] = fmaxf(pmax[1], py);
      pmin[2] = fminf(pmin[2], pz); pmax[2] = fmaxf(pmax[2], pz);

      if (vm) {
        const float d0 = px - gx, d1 = py - gy, d2 = pz - gz;
        sum_diff2 += d0 * d0 + d1 * d1 + d2 * d2;
        cntf += 1.0f;
        gmin[0] = fminf(gmin[0], gx); gmax[0] = fmaxf(gmax[0], gx);
        gmin[1] = fminf(gmin[1], gy); gmax[1] = fmaxf(gmax[1], gy);
        gmin[2] = fminf(gmin[2], gz); gmax[2] = fmaxf(gmax[2], gz);
      }

      if (fi < F_ - 2) {
        const float ax = sN1[3 * t], ay = sN1[3 * t + 1], az = sN1[3 * t + 2];
        const float cx = sN2[3 * t], cy = sN2[3 * t + 1], cz = sN2[3 * t + 2];
        const float a0 = cx - 2.0f * ax + px;
        const float a1 = cy - 2.0f * ay + py;
        const float a2 = cz - 2.0f * az + pz;
        sum_acc2 += a0 * a0 + a1 * a1 + a2 * a2;
      }

#pragma unroll
      for (int v = 0; v < V_; ++v) {
        const float* Pm = sP + v * 12;
        const float a0 = Pm[0] * px + Pm[1] * py + Pm[2]  * pz + Pm[3];
        const float a1 = Pm[4] * px + Pm[5] * py + Pm[6]  * pz + Pm[7];
        const float a2 = Pm[8] * px + Pm[9] * py + Pm[10] * pz + Pm[11];
        const float inv = 1.0f / (a2 + 1e-10f);
        const float dx = a0 * inv - sT[v * 512 + 2 * t];
        const float dy = a1 * inv - sT[v * 512 + 2 * t + 1];
        sum_dist += dx * dx + dy * dy;
      }
    }

    // ---- all waves done reading before next issue overwrites buffers
    asm volatile("s_waitcnt lgkmcnt(0)\n\ts_barrier" ::: "memory");
  }

  // ---------------- wave shuffle reduction (f32, deterministic tree)
#pragma unroll
  for (int o = 32; o > 0; o >>= 1) {
    sum_diff2 += __shfl_down(sum_diff2, o);
    sum_dist  += __shfl_down(sum_dist,  o);
    sum_acc2  += __shfl_down(sum_acc2,  o);
    cntf      += __shfl_down(cntf,      o);
#pragma unroll
    for (int k = 0; k < 3; ++k) {
      gmin[k] = fminf(gmin[k], __shfl_down(gmin[k], o));
      gmax[k] = fmaxf(gmax[k], __shfl_down(gmax[k], o));
      pmin[k] = fminf(pmin[k], __shfl_down(pmin[k], o));
      pmax[k] = fmaxf(pmax[k], __shfl_down(pmax[k], o));
    }
  }

  if (lane == 0) {
    Partial p;
    p.sum_diff2 = sum_diff2; p.sum_dist = sum_dist;
    p.sum_acc2  = sum_acc2;  p.cnt      = cntf;
#pragma unroll
    for (int k = 0; k < 3; ++k) {
      p.gmin[k] = gmin[k]; p.gmax[k] = gmax[k];
      p.pmin[k] = pmin[k]; p.pmax[k] = pmax[k];
    }
    sw[wave] = p;
  }
  __syncthreads();
  if (t == 0) {
    Partial p = sw[0];
#pragma unroll
    for (int w = 1; w < NTHR / 64; ++w) {
      p.sum_diff2 += sw[w].sum_diff2; p.sum_dist += sw[w].sum_dist;
      p.sum_acc2  += sw[w].sum_acc2;  p.cnt      += sw[w].cnt;
#pragma unroll
      for (int k = 0; k < 3; ++k) {
        p.gmin[k] = fminf(p.gmin[k], sw[w].gmin[k]);
        p.gmax[k] = fmaxf(p.gmax[k], sw[w].gmax[k]);
        p.pmin[k] = fminf(p.pmin[k], sw[w].pmin[k]);
        p.pmax[k] = fmaxf(p.pmax[k], sw[w].pmax[k]);
      }
    }
    partials[bid] = p;
  }
}

__global__ __launch_bounds__(NTHR) void loss_final(
    const Partial* __restrict__ partials, float* __restrict__ out)
{
  float sum_diff2 = 0.0f, sum_dist = 0.0f, sum_acc2 = 0.0f, cnt = 0.0f;
  float gmin[3] = { INFINITY,  INFINITY,  INFINITY};
  float gmax[3] = {-INFINITY, -INFINITY, -INFINITY};
  float pmin[3] = { INFINITY,  INFINITY,  INFINITY};
  float pmax[3] = {-INFINITY, -INFINITY, -INFINITY};

  const int tid = threadIdx.x;
  for (int i = tid; i < NBLK; i += NTHR) {   // fixed order -> deterministic
    const Partial p = partials[i];
    sum_diff2 += p.sum_diff2; sum_dist += p.sum_dist;
    sum_acc2  += p.sum_acc2;  cnt      += p.cnt;
#pragma unroll
    for (int k = 0; k < 3; ++k) {
      gmin[k] = fminf(gmin[k], p.gmin[k]); gmax[k] = fmaxf(gmax[k], p.gmax[k]);
      pmin[k] = fminf(pmin[k], p.pmin[k]); pmax[k] = fmaxf(pmax[k], p.pmax[k]);
    }
  }

#pragma unroll
  for (int o = 32; o > 0; o >>= 1) {
    sum_diff2 += __shfl_down(sum_diff2, o);
    sum_dist  += __shfl_down(sum_dist,  o);
    sum_acc2  += __shfl_down(sum_acc2,  o);
    cnt       += __shfl_down(cnt,       o);
#pragma unroll
    for (int k = 0; k < 3; ++k) {
      gmin[k] = fminf(gmin[k], __shfl_down(gmin[k], o));
      gmax[k] = fmaxf(gmax[k], __shfl_down(gmax[k], o));
      pmin[k] = fminf(pmin[k], __shfl_down(pmin[k], o));
      pmax[k] = fmaxf(pmax[k], __shfl_down(pmax[k], o));
    }
  }

  __shared__ Partial sw[NTHR / 64];
  const int lane = tid & 63;
  const int wave = tid >> 6;
  if (lane == 0) {
    Partial p;
    p.sum_diff2 = sum_diff2; p.sum_dist = sum_dist;
    p.sum_acc2  = sum_acc2;  p.cnt      = cnt;
#pragma unroll
    for (int k = 0; k < 3; ++k) {
      p.gmin[k] = gmin[k]; p.gmax[k] = gmax[k];
      p.pmin[k] = pmin[k]; p.pmax[k] = pmax[k];
    }
    sw[wave] = p;
  }
  __syncthreads();

  if (tid == 0) {
    Partial p = sw[0];
#pragma unroll
    for (int w = 1; w < NTHR / 64; ++w) {
      p.sum_diff2 += sw[w].sum_diff2; p.sum_dist += sw[w].sum_dist;
      p.sum_acc2  += sw[w].sum_acc2;  p.cnt      += sw[w].cnt;
#pragma unroll
      for (int k = 0; k < 3; ++k) {
        p.gmin[k] = fminf(p.gmin[k], sw[w].gmin[k]);
        p.gmax[k] = fmaxf(p.gmax[k], sw[w].gmax[k]);
        p.pmin[k] = fminf(p.pmin[k], sw[w].pmin[k]);
        p.pmax[k] = fmaxf(p.pmax[k], sw[w].pmax[k]);
      }
    }

    double sr = -INFINITY;
#pragma unroll
    for (int k = 0; k < 3; ++k) sr = fmax(sr, (double)p.gmax[k] - (double)p.gmin[k]);
    sr += 1e-6;
    const double recon = (double)p.sum_diff2 / fmax((double)p.cnt * 3.0, 1.0) / (sr * sr);

    const double ident = (double)p.sum_dist / 224.0 / ((double)V_ * B_ * F_ * N_ * 2.0);

    double st = -INFINITY;
#pragma unroll
    for (int k = 0; k < 3; ++k) st = fmax(st, (double)p.pmax[k] - (double)p.pmin[k]);
    st += 1e-6;
    const double tloss = (double)p.sum_acc2 / ((double)B_ * (F_ - 2) * N_);
    const double temp = tloss / (st * st);

    const double total = recon + ident + 0.5 * temp;
    out[0] = (float)total;
    out[1] = (float)recon;
    out[2] = (float)ident;
    out[3] = (float)temp;
  }
}

extern "C" void kernel_launch(void* const* d_in, const int* in_sizes, int n_in,
                              void* d_out, int out_size, void* d_ws, size_t ws_size,
                              hipStream_t stream) {
  const float* pred   = (const float*)d_in[0];
  const float* gt     = (const float*)d_in[1];
  const int*   vis    = (const int*)d_in[2];
  const float* P      = (const float*)d_in[3];
  const float* tracks = (const float*)d_in[4];
  float* out = (float*)d_out;
  Partial* partials = (Partial*)d_ws;

  loss_main<<<NBLK, NTHR, 0, stream>>>(pred, gt, vis, P, tracks, partials);
  loss_final<<<1, NTHR, 0, stream>>>(partials, out);
}